// Round 3
// baseline (999.928 us; speedup 1.0000x reference)
//
#include <hip/hip_runtime.h>
#include <cstdint>

// B=2, S=2048, D=1024, NH=16, DH=64, H=1024, M=B*S=4096.
// m97-structure GEMMs: 128x128 tile, BK=64 (f16), global_load_lds staging with
// linear LDS dest + inverse-swizzled global source + XOR-swizzled ds_read_b128.
// Convention: every MFMA operand tile is [outdim][k], k contiguous.

typedef _Float16 half8 __attribute__((ext_vector_type(8)));
typedef float floatx4 __attribute__((ext_vector_type(4)));

__device__ __forceinline__ floatx4 mfma16(half8 a, half8 b, floatx4 c) {
    return __builtin_amdgcn_mfma_f32_16x16x32_f16(a, b, c, 0, 0, 0);
}

__device__ __forceinline__ float gelu_f(float x) {
    return 0.5f * x * (1.0f + erff(x * 0.70710678118654752f));
}

__device__ __forceinline__ void gll16(const void* g, void* l) {
    __builtin_amdgcn_global_load_lds(
        (const __attribute__((address_space(1))) unsigned int*)g,
        (__attribute__((address_space(3))) unsigned int*)l, 16, 0, 0);
}

// Stage ROWS x (GPR*8) f16 tile: linear LDS dest, per-lane source granule
// pre-swizzled g ^= (r&7). Read side must XOR kbyte ^ ((row&7)<<4).
template <int ROWS, int GPR>
__device__ __forceinline__ void stage_gll(char* lds, const _Float16* src, int ld,
                                          int w, int l) {
    constexpr int PW = ROWS * GPR / 4;    // granules per wave
    constexpr int NI = PW / 64;
#pragma unroll
    for (int i = 0; i < NI; i++) {
        const int idx = w * PW + i * 64 + l;
        const int r = idx / GPR;
        const int g = (idx % GPR) ^ (r & 7);
        gll16(src + (size_t)r * ld + g * 8, lds + (w * PW + i * 64) * 16);
    }
}

template <int ROWB>
__device__ __forceinline__ half8 frag(const char* lds, int row, int kbyte) {
    return *(const half8*)(lds + row * ROWB + (kbyte ^ ((row & 7) << 4)));
}

// ---------------- conversion / transpose helpers ----------------

__global__ __launch_bounds__(256) void cvt_f32_f16(const float* __restrict__ src,
                                                   _Float16* __restrict__ dst, int n8) {
    int i = blockIdx.x * 256 + threadIdx.x;
    if (i < n8) {
        float4 a = ((const float4*)src)[i * 2];
        float4 b = ((const float4*)src)[i * 2 + 1];
        half8 h = {(_Float16)a.x, (_Float16)a.y, (_Float16)a.z, (_Float16)a.w,
                   (_Float16)b.x, (_Float16)b.y, (_Float16)b.z, (_Float16)b.w};
        ((half8*)dst)[i] = h;
    }
}

// w [K][N] f32 -> wt [N][K] f16
__global__ __launch_bounds__(256) void wtrans(const float* __restrict__ w,
                                              _Float16* __restrict__ wt, int K, int N) {
    __shared__ float tile[32][33];
    const int n0 = blockIdx.x * 32, k0 = blockIdx.y * 32;
    const int c = threadIdx.x & 31, r0 = threadIdx.x >> 5;
#pragma unroll
    for (int i = 0; i < 4; i++) {
        const int r = r0 + i * 8;
        tile[r][c] = w[(size_t)(k0 + r) * N + n0 + c];
    }
    __syncthreads();
#pragma unroll
    for (int i = 0; i < 4; i++) {
        const int r = r0 + i * 8;
        wt[(size_t)(n0 + r) * K + k0 + c] = (_Float16)tile[c][r];
    }
}

// ---------------- m97-style fp16 GEMM: C[m][n] = sum_k A[m][k]*B[n][k] -------
// A:[M][K], B:[N][K] f16 row-major. 128x128 tile, BK=64, 4 waves (2x2), each
// 64x64 (4x4 16x16x32 frags).

enum { E_QS = 0, E_KS = 1, E_VT = 2, E_GH = 3, E_BGH = 4, E_BGRH = 5, E_GF = 6 };

template <int EPI, bool CONCAT>
__global__ __launch_bounds__(256) void hgemm(
    int M, int N, int K,
    const _Float16* __restrict__ A, int lda, const _Float16* __restrict__ A2,
    const _Float16* __restrict__ B, int ldb,
    void* __restrict__ Cout, const float* __restrict__ bias,
    const float* __restrict__ resF, const _Float16* __restrict__ resH)
{
    __shared__ char ldsA[128 * 128];
    __shared__ char ldsB[128 * 128];
    const int t = threadIdx.x, l = t & 63, w = t >> 6;
    const int wm = w & 1, wn = w >> 1;
    const int lr = l & 15, lg = l >> 4;
    const int brow = blockIdx.y * 128, bcol = blockIdx.x * 128;

    floatx4 acc[4][4];
#pragma unroll
    for (int m = 0; m < 4; m++)
#pragma unroll
        for (int n = 0; n < 4; n++) acc[m][n] = (floatx4){0.f, 0.f, 0.f, 0.f};

    for (int k0 = 0; k0 < K; k0 += 64) {
        const _Float16* Ab = A;
        int kloc = k0;
        if constexpr (CONCAT) {
            if (k0 >= 1024) { Ab = A2; kloc = k0 - 1024; }
        }
        stage_gll<128, 8>(ldsA, Ab + (size_t)brow * lda + kloc, lda, w, l);
        stage_gll<128, 8>(ldsB, B + (size_t)bcol * ldb + k0, ldb, w, l);
        __syncthreads();   // compiler drains vmcnt before s_barrier
#pragma unroll
        for (int kk = 0; kk < 2; kk++) {
            const int kb = kk * 64 + lg * 16;
            half8 af[4], bf[4];
#pragma unroll
            for (int m = 0; m < 4; m++) af[m] = frag<128>(ldsA, wm * 64 + m * 16 + lr, kb);
#pragma unroll
            for (int n = 0; n < 4; n++) bf[n] = frag<128>(ldsB, wn * 64 + n * 16 + lr, kb);
#pragma unroll
            for (int m = 0; m < 4; m++)
#pragma unroll
                for (int n = 0; n < 4; n++)
                    acc[m][n] = mfma16(af[m], bf[n], acc[m][n]);
        }
        __syncthreads();
    }

#pragma unroll
    for (int m = 0; m < 4; m++)
#pragma unroll
        for (int n = 0; n < 4; n++)
#pragma unroll
            for (int r = 0; r < 4; r++) {
                const int grow = brow + wm * 64 + m * 16 + lg * 4 + r;
                const int gcol = bcol + wn * 64 + n * 16 + lr;
                float v = acc[m][n][r];
                if constexpr (EPI == E_QS) v *= 0.125f;
                if constexpr (EPI == E_QS || EPI == E_KS) {
                    const int bb = grow >> 11, s = grow & 2047;
                    const int hh = gcol >> 6, d = gcol & 63;
                    ((_Float16*)Cout)[(((size_t)(bb * 16 + hh) * 2048 + s) << 6) + d] =
                        (_Float16)v;
                } else if constexpr (EPI == E_VT) {
                    const int hh = grow >> 6, d = grow & 63;
                    const int bb = gcol >> 11, s = gcol & 2047;
                    ((_Float16*)Cout)[(((size_t)(bb * 16 + hh) * 64 + d) << 11) + s] =
                        (_Float16)v;
                } else if constexpr (EPI == E_GH) {
                    ((_Float16*)Cout)[(size_t)grow * N + gcol] = (_Float16)gelu_f(v);
                } else if constexpr (EPI == E_BGH) {
                    ((_Float16*)Cout)[(size_t)grow * N + gcol] =
                        (_Float16)gelu_f(v + bias[gcol]);
                } else if constexpr (EPI == E_BGRH) {
                    const float res = (gcol < 1024)
                        ? resF[(size_t)grow * 1024 + gcol]
                        : (float)resH[(size_t)grow * 1024 + (gcol - 1024)];
                    ((_Float16*)Cout)[(size_t)grow * N + gcol] =
                        (_Float16)(gelu_f(v + bias[gcol]) + res);
                } else {  // E_GF
                    ((float*)Cout)[(size_t)grow * N + gcol] = gelu_f(v);
                }
            }
}

// ---------------- fused attention (2-pass, 64-row strip) ---------------------
// Q:[z][s][64], K:[z][s][64], V:[z][d][2048] f16. attn written f32 (coalesced,
// via normalized-f16 LDS roundtrip), QO f16.

__global__ __launch_bounds__(256) void attn_fused(
    const _Float16* __restrict__ Qh, const _Float16* __restrict__ Kh,
    const _Float16* __restrict__ Vh, float* __restrict__ attn,
    _Float16* __restrict__ QOh)
{
    __shared__ char ldsK[128 * 128];   // 128 kv x 64 d
    __shared__ char ldsV[64 * 256];    // 64 d x 128 kv
    __shared__ char ldsP[64 * 256];    // 64 q x 128 kv (f16, normalized)
    __shared__ float rsbuf[2][64];

    const int z = blockIdx.y;
    const int qs0 = blockIdx.x * 64;
    const int t = threadIdx.x, l = t & 63, w = t >> 6;
    const int wm = w & 1, wn = w >> 1;
    const int lr = l & 15, lg = l >> 4;

    const _Float16* Kz = Kh + (size_t)z * 2048 * 64;
    const _Float16* Vz = Vh + (size_t)z * 64 * 2048;

    half8 qf[2][2];
    {
        const _Float16* Qp =
            Qh + (size_t)z * 2048 * 64 + (size_t)(qs0 + wm * 32 + lr) * 64 + lg * 8;
#pragma unroll
        for (int m = 0; m < 2; m++)
#pragma unroll
            for (int kk = 0; kk < 2; kk++)
                qf[m][kk] = *(const half8*)(Qp + m * 16 * 64 + kk * 32);
    }

    // ---- pass A: rowsums of exp(S)
    float rs[2][4] = {};
    for (int it = 0; it < 16; it++) {
        stage_gll<128, 8>(ldsK, Kz + (size_t)it * 128 * 64, 64, w, l);
        __syncthreads();
        half8 kf[4][2];
#pragma unroll
        for (int n16 = 0; n16 < 4; n16++)
#pragma unroll
            for (int kk = 0; kk < 2; kk++)
                kf[n16][kk] = frag<128>(ldsK, wn * 64 + n16 * 16 + lr, kk * 64 + lg * 16);
#pragma unroll
        for (int m = 0; m < 2; m++)
#pragma unroll
            for (int n16 = 0; n16 < 4; n16++) {
                floatx4 s = {0.f, 0.f, 0.f, 0.f};
#pragma unroll
                for (int kk = 0; kk < 2; kk++) s = mfma16(qf[m][kk], kf[n16][kk], s);
#pragma unroll
                for (int r = 0; r < 4; r++) rs[m][r] += __expf(s[r]);
            }
        __syncthreads();
    }
#pragma unroll
    for (int off = 1; off < 16; off <<= 1)
#pragma unroll
        for (int m = 0; m < 2; m++)
#pragma unroll
            for (int r = 0; r < 4; r++) rs[m][r] += __shfl_xor(rs[m][r], off);
    if (lr == 0)
#pragma unroll
        for (int m = 0; m < 2; m++)
#pragma unroll
            for (int r = 0; r < 4; r++)
                rsbuf[wn][wm * 32 + m * 16 + lg * 4 + r] = rs[m][r];
    __syncthreads();
    float rinv[2][4];
#pragma unroll
    for (int m = 0; m < 2; m++)
#pragma unroll
        for (int r = 0; r < 4; r++) {
            const int row = wm * 32 + m * 16 + lg * 4 + r;
            rinv[m][r] = 1.0f / (rsbuf[0][row] + rsbuf[1][row]);
        }
    __syncthreads();

    // ---- pass B: recompute S, normalized P -> ldsP, attn write, P@V
    float* attnz = attn + (size_t)z * 2048 * 2048;
    floatx4 o[2][2] = {{{0.f,0.f,0.f,0.f},{0.f,0.f,0.f,0.f}},
                       {{0.f,0.f,0.f,0.f},{0.f,0.f,0.f,0.f}}};
    for (int it = 0; it < 16; it++) {
        stage_gll<128, 8>(ldsK, Kz + (size_t)it * 128 * 64, 64, w, l);
        stage_gll<64, 16>(ldsV, Vz + it * 128, 2048, w, l);
        __syncthreads();
        half8 kf[4][2];
#pragma unroll
        for (int n16 = 0; n16 < 4; n16++)
#pragma unroll
            for (int kk = 0; kk < 2; kk++)
                kf[n16][kk] = frag<128>(ldsK, wn * 64 + n16 * 16 + lr, kk * 64 + lg * 16);
#pragma unroll
        for (int m = 0; m < 2; m++)
#pragma unroll
            for (int n16 = 0; n16 < 4; n16++) {
                floatx4 s = {0.f, 0.f, 0.f, 0.f};
#pragma unroll
                for (int kk = 0; kk < 2; kk++) s = mfma16(qf[m][kk], kf[n16][kk], s);
#pragma unroll
                for (int r = 0; r < 4; r++) {
                    const float p = __expf(s[r]) * rinv[m][r];
                    const int prow = wm * 32 + m * 16 + lg * 4 + r;
                    const int pcol = wn * 64 + n16 * 16 + lr;
                    *(_Float16*)(ldsP + prow * 256 + ((pcol * 2) ^ ((prow & 7) << 4))) =
                        (_Float16)p;
                }
            }
        __syncthreads();
        // coalesced attn write from ldsP (f16 -> f32)
#pragma unroll
        for (int i = 0; i < 4; i++) {
            const int idx = i * 256 + t;
            const int r = idx >> 4, g = idx & 15;
            half8 ph = *(const half8*)(ldsP + r * 256 + ((g * 16) ^ ((r & 7) << 4)));
            float* dst = attnz + (size_t)(qs0 + r) * 2048 + it * 128 + g * 8;
            float4 lo = {(float)ph[0], (float)ph[1], (float)ph[2], (float)ph[3]};
            float4 hi = {(float)ph[4], (float)ph[5], (float)ph[6], (float)ph[7]};
            *(float4*)dst = lo;
            *(float4*)(dst + 4) = hi;
        }
        // P @ V
#pragma unroll
        for (int kkv = 0; kkv < 4; kkv++) {
            const int kb = kkv * 64 + lg * 16;
            half8 pf[2], vf[2];
#pragma unroll
            for (int m = 0; m < 2; m++) pf[m] = frag<256>(ldsP, wm * 32 + m * 16 + lr, kb);
#pragma unroll
            for (int n = 0; n < 2; n++) vf[n] = frag<256>(ldsV, wn * 32 + n * 16 + lr, kb);
#pragma unroll
            for (int m = 0; m < 2; m++)
#pragma unroll
                for (int n = 0; n < 2; n++) o[m][n] = mfma16(pf[m], vf[n], o[m][n]);
        }
        __syncthreads();
    }

    const int bb = z >> 4, hh = z & 15;
#pragma unroll
    for (int m = 0; m < 2; m++)
#pragma unroll
        for (int n = 0; n < 2; n++)
#pragma unroll
            for (int r = 0; r < 4; r++) {
                const int row = qs0 + wm * 32 + m * 16 + lg * 4 + r;
                const int d = wn * 32 + n * 16 + lr;
                QOh[((size_t)bb * 2048 + row) * 1024 + hh * 64 + d] = (_Float16)o[m][n][r];
            }
}

// ---------------- launch ----------------

extern "C" void kernel_launch(void* const* d_in, const int* in_sizes, int n_in,
                              void* d_out, int out_size, void* d_ws, size_t ws_size,
                              hipStream_t stream)
{
    const float* q_vec = (const float*)d_in[0];
    const float* k_vec = (const float*)d_in[1];
    const float* wq    = (const float*)d_in[2];
    const float* wk    = (const float*)d_in[3];
    const float* wv    = (const float*)d_in[4];
    const float* w_fc1 = (const float*)d_in[5];
    const float* w_m1  = (const float*)d_in[6];
    const float* b_m1  = (const float*)d_in[7];
    const float* w_m2  = (const float*)d_in[8];
    const float* b_m2  = (const float*)d_in[9];
    const float* w_fc2 = (const float*)d_in[10];

    float* out  = (float*)d_out;                      // [2][2048][1024]
    float* attn = out + (size_t)2 * 2048 * 1024;      // [2][16][2048][2048]

    _Float16* W = (_Float16*)d_ws;
    const size_t M1 = 1048576, M2 = 2097152, M4 = 4194304;
    _Float16* qvec_h = W;                  // later reused by hh
    _Float16* kvec_h = W + M4;
    _Float16* WTq  = W + 2 * M4;
    _Float16* WTk  = WTq + M1;
    _Float16* WTv  = WTk + M1;
    _Float16* WTf1 = WTv + M1;
    _Float16* WTm1 = WTf1 + M1;
    _Float16* WTm2 = WTm1 + M2;
    _Float16* WTf2 = WTm2 + M2;
    _Float16* Qh   = WTf2 + M2;
    _Float16* Kh   = Qh + M4;              // later g1h
    _Float16* Vh   = Kh + M4;              // later t1h
    _Float16* QOh  = Vh + M4;
    _Float16* g1h  = Kh;
    _Float16* t1h  = Vh;
    _Float16* hh   = W;                    // reuse qvec+kvec after m1

    dim3 blk(256);

    cvt_f32_f16<<<dim3(2048), blk, 0, stream>>>(q_vec, qvec_h, 524288);
    cvt_f32_f16<<<dim3(2048), blk, 0, stream>>>(k_vec, kvec_h, 524288);
    wtrans<<<dim3(32, 32), blk, 0, stream>>>(wq, WTq, 1024, 1024);
    wtrans<<<dim3(32, 32), blk, 0, stream>>>(wk, WTk, 1024, 1024);
    wtrans<<<dim3(32, 32), blk, 0, stream>>>(wv, WTv, 1024, 1024);
    wtrans<<<dim3(32, 32), blk, 0, stream>>>(w_fc1, WTf1, 1024, 1024);
    wtrans<<<dim3(32, 64), blk, 0, stream>>>(w_m1, WTm1, 2048, 1024);
    wtrans<<<dim3(64, 32), blk, 0, stream>>>(w_m2, WTm2, 1024, 2048);
    wtrans<<<dim3(32, 64), blk, 0, stream>>>(w_fc2, WTf2, 2048, 1024);

    // Q/K projections -> [z][s][64] (Q scaled by 1/8)
    hgemm<E_QS, false><<<dim3(8, 32), blk, 0, stream>>>(
        4096, 1024, 1024, qvec_h, 1024, nullptr, WTq, 1024, Qh, nullptr, nullptr, nullptr);
    hgemm<E_KS, false><<<dim3(8, 32), blk, 0, stream>>>(
        4096, 1024, 1024, kvec_h, 1024, nullptr, WTk, 1024, Kh, nullptr, nullptr, nullptr);
    // V projection transposed -> [z][d][s]
    hgemm<E_VT, false><<<dim3(32, 8), blk, 0, stream>>>(
        1024, 4096, 1024, WTv, 1024, nullptr, kvec_h, 1024, Vh, nullptr, nullptr, nullptr);

    attn_fused<<<dim3(32, 32), blk, 0, stream>>>(Qh, Kh, Vh, attn, QOh);

    hgemm<E_GH, false><<<dim3(8, 32), blk, 0, stream>>>(
        4096, 1024, 1024, QOh, 1024, nullptr, WTf1, 1024, g1h, nullptr, nullptr, nullptr);
    hgemm<E_BGH, true><<<dim3(8, 32), blk, 0, stream>>>(
        4096, 1024, 2048, qvec_h, 1024, g1h, WTm1, 2048, t1h, b_m1, nullptr, nullptr);
    hgemm<E_BGRH, false><<<dim3(16, 32), blk, 0, stream>>>(
        4096, 2048, 1024, t1h, 1024, nullptr, WTm2, 1024, hh, b_m2, q_vec, g1h);
    hgemm<E_GF, false><<<dim3(8, 32), blk, 0, stream>>>(
        4096, 1024, 2048, hh, 2048, nullptr, WTf2, 2048, out, nullptr, nullptr, nullptr);
}

// Round 4
// 925.829 us; speedup vs baseline: 1.0800x; 1.0800x over previous
//
#include <hip/hip_runtime.h>
#include <cstdint>

// B=2, S=2048, D=1024, NH=16, DH=64, H=1024, M=B*S=4096.
// 2-phase double-buffered f16 MFMA GEMMs (stage-before-compute), 8 waves/block.
// Convention: every MFMA operand tile is [outdim][k], k contiguous.
// LDS rule #21: linear LDS dest for global_load_lds + inverse-swizzled global
// source granule (g ^= r&7) + XOR-swizzled ds_read (kbyte ^ ((row&7)<<4)).

typedef _Float16 half8 __attribute__((ext_vector_type(8)));
typedef float floatx4 __attribute__((ext_vector_type(4)));

__device__ __forceinline__ floatx4 mfma16(half8 a, half8 b, floatx4 c) {
    return __builtin_amdgcn_mfma_f32_16x16x32_f16(a, b, c, 0, 0, 0);
}

__device__ __forceinline__ float gelu_f(float x) {
    return 0.5f * x * (1.0f + erff(x * 0.70710678118654752f));
}

__device__ __forceinline__ void gll16(const void* g, void* l) {
    __builtin_amdgcn_global_load_lds(
        (const __attribute__((address_space(1))) unsigned int*)g,
        (__attribute__((address_space(3))) unsigned int*)l, 16, 0, 0);
}

// Stage ROWS x (GPR*8) f16 tile with NW waves.
template <int ROWS, int GPR, int NW>
__device__ __forceinline__ void stage_gll(char* lds, const _Float16* src, int ld,
                                          int w, int l) {
    constexpr int PW = ROWS * GPR / NW;   // granules per wave
    constexpr int NI = PW / 64;
#pragma unroll
    for (int i = 0; i < NI; i++) {
        const int idx = w * PW + i * 64 + l;
        const int r = idx / GPR;
        const int g = (idx % GPR) ^ (r & 7);
        gll16(src + (size_t)r * ld + g * 8, lds + (w * PW + i * 64) * 16);
    }
}

template <int ROWB>
__device__ __forceinline__ half8 frag(const char* lds, int row, int kbyte) {
    return *(const half8*)(lds + row * ROWB + (kbyte ^ ((row & 7) << 4)));
}

// ---------------- conversion / transpose helpers ----------------

__global__ __launch_bounds__(256) void cvt_f32_f16(const float* __restrict__ src,
                                                   _Float16* __restrict__ dst, int n8) {
    int i = blockIdx.x * 256 + threadIdx.x;
    if (i < n8) {
        float4 a = ((const float4*)src)[i * 2];
        float4 b = ((const float4*)src)[i * 2 + 1];
        half8 h = {(_Float16)a.x, (_Float16)a.y, (_Float16)a.z, (_Float16)a.w,
                   (_Float16)b.x, (_Float16)b.y, (_Float16)b.z, (_Float16)b.w};
        ((half8*)dst)[i] = h;
    }
}

// w [K][N] f32 -> wt [N][K] f16
__global__ __launch_bounds__(256) void wtrans(const float* __restrict__ w,
                                              _Float16* __restrict__ wt, int K, int N) {
    __shared__ float tile[32][33];
    const int n0 = blockIdx.x * 32, k0 = blockIdx.y * 32;
    const int c = threadIdx.x & 31, r0 = threadIdx.x >> 5;
#pragma unroll
    for (int i = 0; i < 4; i++) {
        const int r = r0 + i * 8;
        tile[r][c] = w[(size_t)(k0 + r) * N + n0 + c];
    }
    __syncthreads();
#pragma unroll
    for (int i = 0; i < 4; i++) {
        const int r = r0 + i * 8;
        wt[(size_t)(n0 + r) * K + k0 + c] = (_Float16)tile[c][r];
    }
}

// ---------------- 2-phase dbuf fp16 GEMM: C[m][n] = sum_k A[m][k]*B[n][k] ----
// A:[M][K], B:[N][K] f16. 128x128 tile, BK=64, dbuf LDS (64 KB), 8 waves,
// each wave 64x32 (4x2 frags). Stage t+1 issued BEFORE compute t.

enum { E_QK = 0, E_VT = 2, E_GH = 3, E_BGH = 4, E_BGRH = 5, E_GF = 6 };

template <int EPI, bool CONCAT>
__global__ __launch_bounds__(512) void hgemm(
    int M, int N, int K,
    const _Float16* __restrict__ A, int lda, const _Float16* __restrict__ Aalt,
    const _Float16* __restrict__ B, int ldb, const _Float16* __restrict__ Balt,
    void* __restrict__ Cout, void* __restrict__ Coutalt,
    const float* __restrict__ bias,
    const float* __restrict__ resF, const _Float16* __restrict__ resH)
{
    __shared__ char ldsA[2 * 16384];
    __shared__ char ldsB[2 * 16384];
    const int t = threadIdx.x, l = t & 63, w = t >> 6;   // w 0..7
    const int wm = w & 1, wn = w >> 1;                   // 2 x 4 wave grid
    const int lr = l & 15, lg = l >> 4;
    const int brow = blockIdx.y * 128, bcol = blockIdx.x * 128;
    const int zsel = blockIdx.z;

    const _Float16* Abase = A;
    const _Float16* Bbase = B;
    if constexpr (EPI == E_QK) {
        if (zsel) { Abase = Aalt; Bbase = Balt; }
    }

    const int nt = K / 64;

    auto stageT = [&](int tt, int buf) {
        const int k0 = tt * 64;
        const _Float16* Ab = Abase;
        int kloc = k0;
        if constexpr (CONCAT) {
            if (k0 >= 1024) { Ab = Aalt; kloc = k0 - 1024; }
        }
        stage_gll<128, 8, 8>(ldsA + buf * 16384, Ab + (size_t)brow * lda + kloc, lda, w, l);
        stage_gll<128, 8, 8>(ldsB + buf * 16384, Bbase + (size_t)bcol * ldb + k0, ldb, w, l);
    };

    floatx4 acc[4][2];
#pragma unroll
    for (int m = 0; m < 4; m++)
#pragma unroll
        for (int n = 0; n < 2; n++) acc[m][n] = (floatx4){0.f, 0.f, 0.f, 0.f};

    stageT(0, 0);
    __syncthreads();

    for (int tt = 0; tt < nt; ++tt) {
        const int cur = tt & 1;
        if (tt + 1 < nt) stageT(tt + 1, cur ^ 1);   // issue next tile first
        const char* cA = ldsA + cur * 16384;
        const char* cB = ldsB + cur * 16384;
#pragma unroll
        for (int kk = 0; kk < 2; kk++) {
            const int kb = kk * 64 + lg * 16;
            half8 af[4], bf[2];
#pragma unroll
            for (int m = 0; m < 4; m++) af[m] = frag<128>(cA, wm * 64 + m * 16 + lr, kb);
#pragma unroll
            for (int n = 0; n < 2; n++) bf[n] = frag<128>(cB, wn * 32 + n * 16 + lr, kb);
#pragma unroll
            for (int m = 0; m < 4; m++)
#pragma unroll
                for (int n = 0; n < 2; n++)
                    acc[m][n] = mfma16(af[m], bf[n], acc[m][n]);
        }
        __syncthreads();   // vmcnt(0)+lgkmcnt(0)+barrier: next tile landed, cur free
    }

#pragma unroll
    for (int m = 0; m < 4; m++)
#pragma unroll
        for (int n = 0; n < 2; n++)
#pragma unroll
            for (int r = 0; r < 4; r++) {
                const int grow = brow + wm * 64 + m * 16 + lg * 4 + r;
                const int gcol = bcol + wn * 32 + n * 16 + lr;
                float v = acc[m][n][r];
                if constexpr (EPI == E_QK) {
                    const int bb = grow >> 11, s = grow & 2047;
                    const int hh = gcol >> 6, d = gcol & 63;
                    _Float16* dst = zsel ? (_Float16*)Coutalt : (_Float16*)Cout;
                    if (!zsel) v *= 0.125f;   // fold 1/sqrt(64) into Q
                    dst[(((size_t)(bb * 16 + hh) * 2048 + s) << 6) + d] = (_Float16)v;
                } else if constexpr (EPI == E_VT) {
                    const int hh = grow >> 6, d = grow & 63;
                    const int bb = gcol >> 11, s = gcol & 2047;
                    ((_Float16*)Cout)[(((size_t)(bb * 16 + hh) * 64 + d) << 11) + s] =
                        (_Float16)v;
                } else if constexpr (EPI == E_GH) {
                    ((_Float16*)Cout)[(size_t)grow * N + gcol] = (_Float16)gelu_f(v);
                } else if constexpr (EPI == E_BGH) {
                    ((_Float16*)Cout)[(size_t)grow * N + gcol] =
                        (_Float16)gelu_f(v + bias[gcol]);
                } else if constexpr (EPI == E_BGRH) {
                    const float res = (gcol < 1024)
                        ? resF[(size_t)grow * 1024 + gcol]
                        : (float)resH[(size_t)grow * 1024 + (gcol - 1024)];
                    ((_Float16*)Cout)[(size_t)grow * N + gcol] =
                        (_Float16)(gelu_f(v + bias[gcol]) + res);
                } else {  // E_GF
                    ((float*)Cout)[(size_t)grow * N + gcol] = gelu_f(v);
                }
            }
}

// ---------------- fused attention (2-pass, 64-row strip, 4 waves) ------------
// Q:[z][s][64], K:[z][s][64], V:[z][d][2048] f16. attn f32 direct from regs.

__global__ __launch_bounds__(256) void attn_fused(
    const _Float16* __restrict__ Qh, const _Float16* __restrict__ Kh,
    const _Float16* __restrict__ Vh, float* __restrict__ attn,
    _Float16* __restrict__ QOh)
{
    __shared__ char ldsK[16384];   // 128 kv x 64 d (pass A: dbuf partner = ldsV)
    __shared__ char ldsV[16384];   // 64 d x 128 kv
    __shared__ char ldsP[16384];   // 64 q x 128 kv f16
    __shared__ float rsbuf[2][64];

    const int z = blockIdx.y;
    const int qs0 = blockIdx.x * 64;
    const int t = threadIdx.x, l = t & 63, w = t >> 6;
    const int wm = w & 1, wn = w >> 1;
    const int lr = l & 15, lg = l >> 4;

    const _Float16* Kz = Kh + (size_t)z * 2048 * 64;
    const _Float16* Vz = Vh + (size_t)z * 64 * 2048;

    half8 qf[2][2];
    {
        const _Float16* Qp =
            Qh + (size_t)z * 2048 * 64 + (size_t)(qs0 + wm * 32 + lr) * 64 + lg * 8;
#pragma unroll
        for (int m = 0; m < 2; m++)
#pragma unroll
            for (int kk = 0; kk < 2; kk++)
                qf[m][kk] = *(const half8*)(Qp + m * 16 * 64 + kk * 32);
    }

    // ---- pass A: rowsums of exp(S), double-buffered across ldsK/ldsV
    float rs[2][4] = {};
    stage_gll<128, 8, 4>(ldsK, Kz, 64, w, l);
    __syncthreads();
    for (int it = 0; it < 16; it++) {
        const char* cur = (it & 1) ? ldsV : ldsK;
        char* nxt = (it & 1) ? ldsK : ldsV;
        if (it < 15) stage_gll<128, 8, 4>(nxt, Kz + (size_t)(it + 1) * 128 * 64, 64, w, l);
#pragma unroll
        for (int m = 0; m < 2; m++)
#pragma unroll
            for (int n16 = 0; n16 < 4; n16++) {
                floatx4 s = {0.f, 0.f, 0.f, 0.f};
#pragma unroll
                for (int kk = 0; kk < 2; kk++)
                    s = mfma16(qf[m][kk],
                               frag<128>(cur, wn * 64 + n16 * 16 + lr, kk * 64 + lg * 16),
                               s);
#pragma unroll
                for (int r = 0; r < 4; r++) rs[m][r] += __expf(s[r]);
            }
        __syncthreads();
    }
#pragma unroll
    for (int off = 1; off < 16; off <<= 1)
#pragma unroll
        for (int m = 0; m < 2; m++)
#pragma unroll
            for (int r = 0; r < 4; r++) rs[m][r] += __shfl_xor(rs[m][r], off);
    if (lr == 0)
#pragma unroll
        for (int m = 0; m < 2; m++)
#pragma unroll
            for (int r = 0; r < 4; r++)
                rsbuf[wn][wm * 32 + m * 16 + lg * 4 + r] = rs[m][r];
    __syncthreads();
    float rinv[2][4];
#pragma unroll
    for (int m = 0; m < 2; m++)
#pragma unroll
        for (int r = 0; r < 4; r++) {
            const int row = wm * 32 + m * 16 + lg * 4 + r;
            rinv[m][r] = 1.0f / (rsbuf[0][row] + rsbuf[1][row]);
        }
    __syncthreads();

    // ---- pass B: recompute S, direct attn f32 store, P->ldsP, P@V
    float* attnz = attn + (size_t)z * 2048 * 2048;
    floatx4 o[2][2] = {{{0.f,0.f,0.f,0.f},{0.f,0.f,0.f,0.f}},
                       {{0.f,0.f,0.f,0.f},{0.f,0.f,0.f,0.f}}};
    stage_gll<128, 8, 4>(ldsK, Kz, 64, w, l);
    stage_gll<64, 16, 4>(ldsV, Vz, 2048, w, l);
    __syncthreads();
    for (int it = 0; it < 16; it++) {
        // S + exp + attn store + P write
#pragma unroll
        for (int m = 0; m < 2; m++)
#pragma unroll
            for (int n16 = 0; n16 < 4; n16++) {
                floatx4 s = {0.f, 0.f, 0.f, 0.f};
#pragma unroll
                for (int kk = 0; kk < 2; kk++)
                    s = mfma16(qf[m][kk],
                               frag<128>(ldsK, wn * 64 + n16 * 16 + lr, kk * 64 + lg * 16),
                               s);
#pragma unroll
                for (int r = 0; r < 4; r++) {
                    const float p = __expf(s[r]) * rinv[m][r];
                    const int prow = wm * 32 + m * 16 + lg * 4 + r;
                    const int pcol = wn * 64 + n16 * 16 + lr;
                    attnz[(size_t)(qs0 + prow) * 2048 + it * 128 + pcol] = p;
                    *(_Float16*)(ldsP + prow * 256 + ((pcol * 2) ^ ((prow & 7) << 4))) =
                        (_Float16)p;
                }
            }
        __syncthreads();   // P visible; ldsK free
        // prefetch P/V fragments to registers
        half8 pf[2][4], vf[2][4];
#pragma unroll
        for (int kkv = 0; kkv < 4; kkv++) {
            const int kb = kkv * 64 + lg * 16;
#pragma unroll
            for (int m = 0; m < 2; m++) pf[m][kkv] = frag<256>(ldsP, wm * 32 + m * 16 + lr, kb);
#pragma unroll
            for (int n = 0; n < 2; n++) vf[n][kkv] = frag<256>(ldsV, wn * 32 + n * 16 + lr, kb);
        }
        __syncthreads();   // all reads drained; ldsV free
        if (it < 15) {     // stage next K/V, overlapping the PV MFMA cluster
            stage_gll<128, 8, 4>(ldsK, Kz + (size_t)(it + 1) * 128 * 64, 64, w, l);
            stage_gll<64, 16, 4>(ldsV, Vz + (it + 1) * 128, 2048, w, l);
        }
#pragma unroll
        for (int kkv = 0; kkv < 4; kkv++)
#pragma unroll
            for (int m = 0; m < 2; m++)
#pragma unroll
                for (int n = 0; n < 2; n++)
                    o[m][n] = mfma16(pf[m][kkv], vf[n][kkv], o[m][n]);
        __syncthreads();   // vmcnt drained: next K/V landed
    }

    const int bb = z >> 4, hh = z & 15;
#pragma unroll
    for (int m = 0; m < 2; m++)
#pragma unroll
        for (int n = 0; n < 2; n++)
#pragma unroll
            for (int r = 0; r < 4; r++) {
                const int row = qs0 + wm * 32 + m * 16 + lg * 4 + r;
                const int d = wn * 32 + n * 16 + lr;
                QOh[((size_t)bb * 2048 + row) * 1024 + hh * 64 + d] = (_Float16)o[m][n][r];
            }
}

// ---------------- launch ----------------

extern "C" void kernel_launch(void* const* d_in, const int* in_sizes, int n_in,
                              void* d_out, int out_size, void* d_ws, size_t ws_size,
                              hipStream_t stream)
{
    const float* q_vec = (const float*)d_in[0];
    const float* k_vec = (const float*)d_in[1];
    const float* wq    = (const float*)d_in[2];
    const float* wk    = (const float*)d_in[3];
    const float* wv    = (const float*)d_in[4];
    const float* w_fc1 = (const float*)d_in[5];
    const float* w_m1  = (const float*)d_in[6];
    const float* b_m1  = (const float*)d_in[7];
    const float* w_m2  = (const float*)d_in[8];
    const float* b_m2  = (const float*)d_in[9];
    const float* w_fc2 = (const float*)d_in[10];

    float* out  = (float*)d_out;                      // [2][2048][1024]
    float* attn = out + (size_t)2 * 2048 * 1024;      // [2][16][2048][2048]

    _Float16* W = (_Float16*)d_ws;
    const size_t M1 = 1048576, M2 = 2097152, M4 = 4194304;
    _Float16* qvec_h = W;                  // later reused by hh
    _Float16* kvec_h = W + M4;
    _Float16* WTq  = W + 2 * M4;
    _Float16* WTk  = WTq + M1;
    _Float16* WTv  = WTk + M1;
    _Float16* WTf1 = WTv + M1;
    _Float16* WTm1 = WTf1 + M1;
    _Float16* WTm2 = WTm1 + M2;
    _Float16* WTf2 = WTm2 + M2;
    _Float16* Qh   = WTf2 + M2;
    _Float16* Kh   = Qh + M4;              // later g1h
    _Float16* Vh   = Kh + M4;              // later t1h
    _Float16* QOh  = Vh + M4;
    _Float16* g1h  = Kh;
    _Float16* t1h  = Vh;
    _Float16* hh   = W;                    // reuse qvec+kvec after m1

    dim3 blk(256), blk8(512);

    cvt_f32_f16<<<dim3(2048), blk, 0, stream>>>(q_vec, qvec_h, 524288);
    cvt_f32_f16<<<dim3(2048), blk, 0, stream>>>(k_vec, kvec_h, 524288);
    wtrans<<<dim3(32, 32), blk, 0, stream>>>(wq, WTq, 1024, 1024);
    wtrans<<<dim3(32, 32), blk, 0, stream>>>(wk, WTk, 1024, 1024);
    wtrans<<<dim3(32, 32), blk, 0, stream>>>(wv, WTv, 1024, 1024);
    wtrans<<<dim3(32, 32), blk, 0, stream>>>(w_fc1, WTf1, 1024, 1024);
    wtrans<<<dim3(32, 64), blk, 0, stream>>>(w_m1, WTm1, 2048, 1024);
    wtrans<<<dim3(64, 32), blk, 0, stream>>>(w_m2, WTm2, 1024, 2048);
    wtrans<<<dim3(32, 64), blk, 0, stream>>>(w_fc2, WTf2, 2048, 1024);

    // Q (z=0) and K (z=1) projections batched -> [z16][s][64]
    hgemm<E_QK, false><<<dim3(8, 32, 2), blk8, 0, stream>>>(
        4096, 1024, 1024, qvec_h, 1024, kvec_h, WTq, 1024, WTk,
        Qh, Kh, nullptr, nullptr, nullptr);
    // V projection transposed -> [z16][d][s]
    hgemm<E_VT, false><<<dim3(32, 8, 1), blk8, 0, stream>>>(
        1024, 4096, 1024, WTv, 1024, nullptr, kvec_h, 1024, nullptr,
        Vh, nullptr, nullptr, nullptr, nullptr);

    attn_fused<<<dim3(32, 32), blk, 0, stream>>>(Qh, Kh, Vh, attn, QOh);

    hgemm<E_GH, false><<<dim3(8, 32, 1), blk8, 0, stream>>>(
        4096, 1024, 1024, QOh, 1024, nullptr, WTf1, 1024, nullptr,
        g1h, nullptr, nullptr, nullptr, nullptr);
    hgemm<E_BGH, true><<<dim3(8, 32, 1), blk8, 0, stream>>>(
        4096, 1024, 2048, qvec_h, 1024, g1h, WTm1, 2048, nullptr,
        t1h, nullptr, b_m1, nullptr, nullptr);
    hgemm<E_BGRH, false><<<dim3(16, 32, 1), blk8, 0, stream>>>(
        4096, 2048, 1024, t1h, 1024, nullptr, WTm2, 1024, nullptr,
        hh, nullptr, b_m2, q_vec, g1h);
    hgemm<E_GF, false><<<dim3(8, 32, 1), blk8, 0, stream>>>(
        4096, 1024, 2048, hh, 2048, nullptr, WTf2, 2048, nullptr,
        out, nullptr, nullptr, nullptr, nullptr);
}